// Round 2
// baseline (68.646 us; speedup 1.0000x reference)
//
#include <hip/hip_runtime.h>

// VectorMSE (actually InfoNCE/contrastive MVN loss):
// loss = mean_i( LSE_j((p_i.g_j - 0.5|g_j|^2)/nv) - (p_i.g_i - 0.5|g_i|^2)/nv ) * 2nv
// B = 8192, D = 256, fp32 inputs, scalar fp32 output.

typedef short short8 __attribute__((ext_vector_type(8)));
typedef float f32x4 __attribute__((ext_vector_type(4)));

#define LN2F 0.6931471805599453f
#define LOG2EF 1.4426950408889634f
#define NB 8192
#define ND 256
#define NCHUNK 16   // column chunks; chunk = 512 cols = 8 tiles of 64

__device__ __forceinline__ unsigned short f2bf(float f) {
  unsigned u = __float_as_uint(f);
  u += 0x7FFFu + ((u >> 16) & 1u);   // round-to-nearest-even
  return (unsigned short)(u >> 16);
}

// ---- kernel 1: convert to bf16 + exact fp32 row stats --------------------
// one wave per row; lane holds 4 contiguous elems (float4).
__global__ __launch_bounds__(256) void vmse_prep(
    const float* __restrict__ pred, const float* __restrict__ gt,
    unsigned short* __restrict__ Ah, unsigned short* __restrict__ Bh,
    float* __restrict__ diag, float* __restrict__ gnorm)
{
  const int row = blockIdx.x * 4 + (threadIdx.x >> 6);
  const int lane = threadIdx.x & 63;
  const float4 p = *(const float4*)(pred + row * ND + lane * 4);
  const float4 g = *(const float4*)(gt   + row * ND + lane * 4);
  ushort4 pa, ga;
  pa.x = f2bf(p.x); pa.y = f2bf(p.y); pa.z = f2bf(p.z); pa.w = f2bf(p.w);
  ga.x = f2bf(g.x); ga.y = f2bf(g.y); ga.z = f2bf(g.z); ga.w = f2bf(g.w);
  *(ushort4*)(Ah + row * ND + lane * 4) = pa;
  *(ushort4*)(Bh + row * ND + lane * 4) = ga;
  float dd = p.x * g.x + p.y * g.y + p.z * g.z + p.w * g.w;
  float gg = g.x * g.x + g.y * g.y + g.z * g.z + g.w * g.w;
  #pragma unroll
  for (int off = 1; off < 64; off <<= 1) {
    dd += __shfl_xor(dd, off);
    gg += __shfl_xor(gg, off);
  }
  if (lane == 0) { diag[row] = dd; gnorm[row] = gg; }
}

// ---- kernel 2: fused GEMM + online base-2 LSE ----------------------------
// grid 512 = 32 row-blocks x 16 column chunks. 256 threads = 4 waves.
// Each wave owns 64 pred rows (4 n-subtiles of 16); P frags resident in VGPRs.
// G tiles (64 cols x 256 K, bf16) double-buffered in LDS with 16B-chunk XOR
// swizzle (kc ^= row&7) so the stride-512B ds_read_b128 frag reads spread
// uniformly over all 8 bank groups.
// Swapped mfma(G,P): C/D col=lane&15 -> pred idx, row=(lane>>4)*4+reg -> gt idx,
// so the row-LSE is lane-local; cross-lane merge = shfl_xor 16,32.
__global__ __launch_bounds__(256, 2) void vmse_main(
    const unsigned short* __restrict__ Ah, const unsigned short* __restrict__ Bh,
    const float* __restrict__ gnorm, const float* __restrict__ sigma,
    float* __restrict__ partial)
{
  __shared__ unsigned short lds[2][64 * ND];   // 2 x 32 KB
  const int tid = threadIdx.x;
  const int lane = tid & 63;
  const int wid = tid >> 6;
  const int rb = blockIdx.x & 31;     // row block (256 rows)
  const int ch = blockIdx.x >> 5;     // column chunk (512 cols)
  const int r15 = lane & 15;
  const int hi = lane >> 4;
  const int swz = (lane & 7) << 3;    // XOR mask in ushort units (bits 3-5)

  const float nv = sigma[0] * sigma[0];
  const float s = LOG2EF / nv;        // scale to base-2 logits

  // P fragments: B-operand layout: n = lane&15, k = (lane>>4)*8 + e
  short8 pf[4][8];
  #pragma unroll
  for (int ns = 0; ns < 4; ++ns) {
    const unsigned short* prow =
        Ah + (size_t)((rb * 256) + (wid * 64) + (ns * 16) + r15) * ND + hi * 8;
    #pragma unroll
    for (int kk = 0; kk < 8; ++kk)
      pf[ns][kk] = *(const short8*)(prow + kk * 32);
  }

  const int j0 = ch * 512;

  float m2[4], l2[4];
  #pragma unroll
  for (int ns = 0; ns < 4; ++ns) { m2[ns] = -3.0e38f; l2[ns] = 0.0f; }

  short8 st[8];
  // prologue: stage tile 0 (reg-staged; write side applies the same swizzle)
  {
    const unsigned short* src0 = Bh + (size_t)j0 * ND;
    #pragma unroll
    for (int it = 0; it < 8; ++it)
      st[it] = *(const short8*)(src0 + (it * 256 + tid) * 8);
    #pragma unroll
    for (int it = 0; it < 8; ++it) {
      const int c = it * 256 + tid;
      const int r = c >> 5, kc = c & 31;
      *(short8*)(&lds[0][r * ND + ((kc ^ (r & 7)) * 8)]) = st[it];
    }
  }
  __syncthreads();

  for (int t = 0; t < 8; ++t) {
    const int buf = t & 1;
    if (t + 1 < 8) {   // T14: issue next tile's global loads before compute
      const unsigned short* src0 = Bh + (size_t)(j0 + (t + 1) * 64) * ND;
      #pragma unroll
      for (int it = 0; it < 8; ++it)
        st[it] = *(const short8*)(src0 + (it * 256 + tid) * 8);
    }

    const unsigned short* ldsb = &lds[buf][0];
    #pragma unroll
    for (int ms = 0; ms < 4; ++ms) {
      // gnorm for gt rows j = j0 + t*64 + ms*16 + hi*4 + e (broadcast dwordx4)
      const float4 g4 = *(const float4*)(gnorm + j0 + t * 64 + ms * 16 + hi * 4);
      f32x4 acc[4];
      #pragma unroll
      for (int ns = 0; ns < 4; ++ns) acc[ns] = (f32x4){0.f, 0.f, 0.f, 0.f};
      const int rowb = (ms * 16 + r15) * ND;
      #pragma unroll
      for (int kk = 0; kk < 8; ++kk) {
        const short8 gf =
            *(const short8*)(ldsb + rowb + (((kk * 32) + (hi * 8)) ^ swz));
        acc[0] = __builtin_amdgcn_mfma_f32_16x16x32_bf16(gf, pf[0][kk], acc[0], 0, 0, 0);
        acc[1] = __builtin_amdgcn_mfma_f32_16x16x32_bf16(gf, pf[1][kk], acc[1], 0, 0, 0);
        acc[2] = __builtin_amdgcn_mfma_f32_16x16x32_bf16(gf, pf[2][kk], acc[2], 0, 0, 0);
        acc[3] = __builtin_amdgcn_mfma_f32_16x16x32_bf16(gf, pf[3][kk], acc[3], 0, 0, 0);
      }
      const float gh0 = g4.x * 0.5f * s, gh1 = g4.y * 0.5f * s;
      const float gh2 = g4.z * 0.5f * s, gh3 = g4.w * 0.5f * s;
      #pragma unroll
      for (int ns = 0; ns < 4; ++ns) {
        const float z0 = acc[ns][0] * s - gh0;
        const float z1 = acc[ns][1] * s - gh1;
        const float z2 = acc[ns][2] * s - gh2;
        const float z3 = acc[ns][3] * s - gh3;
        const float tmax = fmaxf(fmaxf(z0, z1), fmaxf(z2, z3));
        if (tmax > m2[ns]) { l2[ns] *= exp2f(m2[ns] - tmax); m2[ns] = tmax; }  // defer-max
        const float e0 = exp2f(z0 - m2[ns]);
        const float e1 = exp2f(z1 - m2[ns]);
        const float e2 = exp2f(z2 - m2[ns]);
        const float e3 = exp2f(z3 - m2[ns]);
        l2[ns] += (e0 + e1) + (e2 + e3);
      }
    }
    __syncthreads();                    // all waves done reading lds[buf^1]-to-be
    if (t + 1 < 8) {
      const int nb = buf ^ 1;
      #pragma unroll
      for (int it = 0; it < 8; ++it) {
        const int c = it * 256 + tid;
        const int r = c >> 5, kc = c & 31;
        *(short8*)(&lds[nb][r * ND + ((kc ^ (r & 7)) * 8)]) = st[it];
      }
    }
    __syncthreads();                    // staged tile visible to all
  }

  // combine lanes {i, i+16, i+32, i+48} (same pred row), write base-2 partial LSE
  #pragma unroll
  for (int ns = 0; ns < 4; ++ns) {
    float m = m2[ns], l = l2[ns];
    #pragma unroll
    for (int off = 16; off <= 32; off <<= 1) {
      const float om = __shfl_xor(m, off);
      const float ol = __shfl_xor(l, off);
      const float nm = fmaxf(m, om);
      l = l * exp2f(m - nm) + ol * exp2f(om - nm);
      m = nm;
    }
    if (hi == 0) {
      const int row = rb * 256 + wid * 64 + ns * 16 + r15;
      partial[row * NCHUNK + ch] = m + log2f(l);
    }
  }
}

// ---- kernel 3: per-row combine of chunk partials + diagonal --------------
__global__ __launch_bounds__(256) void vmse_combine(
    const float* __restrict__ partial, const float* __restrict__ diag,
    const float* __restrict__ gnorm, const float* __restrict__ sigma,
    float* __restrict__ bsum)
{
  const int r = blockIdx.x * 256 + threadIdx.x;
  const float nv = sigma[0] * sigma[0];
  float p[NCHUNK];
  float M = -3.0e38f;
  #pragma unroll
  for (int c = 0; c < NCHUNK; ++c) { p[c] = partial[r * NCHUNK + c]; M = fmaxf(M, p[c]); }
  float ssum = 0.f;
  #pragma unroll
  for (int c = 0; c < NCHUNK; ++c) ssum += exp2f(p[c] - M);
  const float lse2 = M + log2f(ssum);          // base-2 LSE of z*log2e
  const float zii = (diag[r] - 0.5f * gnorm[r]) / nv;
  float contrib = LN2F * lse2 - zii;           // lse_e - z_ii
  #pragma unroll
  for (int off = 1; off < 64; off <<= 1) contrib += __shfl_xor(contrib, off);
  __shared__ float wsum[4];
  if ((threadIdx.x & 63) == 0) wsum[threadIdx.x >> 6] = contrib;
  __syncthreads();
  if (threadIdx.x == 0)
    bsum[blockIdx.x] = (wsum[0] + wsum[1]) + (wsum[2] + wsum[3]);
}

// ---- kernel 4: deterministic finalize ------------------------------------
__global__ __launch_bounds__(64) void vmse_final(
    const float* __restrict__ bsum, const float* __restrict__ sigma,
    float* __restrict__ out)
{
  const int lane = threadIdx.x;
  float v = (lane < 32) ? bsum[lane] : 0.f;
  #pragma unroll
  for (int off = 1; off < 64; off <<= 1) v += __shfl_xor(v, off);
  if (lane == 0) {
    const float nv = sigma[0] * sigma[0];
    out[0] = v * (2.0f * nv / (float)NB);
  }
}

extern "C" void kernel_launch(void* const* d_in, const int* in_sizes, int n_in,
                              void* d_out, int out_size, void* d_ws, size_t ws_size,
                              hipStream_t stream)
{
  const float* pred  = (const float*)d_in[0];
  const float* gt    = (const float*)d_in[1];
  const float* sigma = (const float*)d_in[2];
  char* ws = (char*)d_ws;
  // ws layout: Ah 4MB | Bh 4MB | gnorm 32KB | diag 32KB | partial 512KB | bsum
  unsigned short* Ah = (unsigned short*)(ws);
  unsigned short* Bh = (unsigned short*)(ws + (4u << 20));
  float* gnorm   = (float*)(ws + (8u << 20));
  float* diag    = (float*)(ws + (8u << 20) + (32u << 10));
  float* partial = (float*)(ws + (8u << 20) + (64u << 10));
  float* bsum    = (float*)(ws + (8u << 20) + (576u << 10));

  vmse_prep<<<NB / 4, 256, 0, stream>>>(pred, gt, Ah, Bh, diag, gnorm);
  vmse_main<<<32 * NCHUNK, 256, 0, stream>>>(Ah, Bh, gnorm, sigma, partial);
  vmse_combine<<<NB / 256, 256, 0, stream>>>(partial, diag, gnorm, sigma, bsum);
  vmse_final<<<1, 64, 0, stream>>>(bsum, sigma, (float*)d_out);
}